// Round 10
// baseline (174.589 us; speedup 1.0000x reference)
//
#include <hip/hip_runtime.h>

#define BATCH 8192
#define NE 127
#define RODS 32            // rods per block = one wave, 1 compute-lane per rod
#define NCH 32             // 31 full 4-edge chunks + 1 tail chunk (3 edges) = 127

// LDS layout (dword offsets within one buffer). Padded strides (37/13/5) are
// coprime-ish with 32 banks => <=2-way conflicts on compute reads (free).
#define MS_OFF   0         // 64 rows x 37  = 2368   (ms row window, 36 dw + pad)
#define VIN_OFF  2368      // 32 rods x 13 -> padded to 448
#define SC_OFF   2816      // 64 rows x 5   = 320
#define NL_OFF   3136      // 32 rods x 5  -> padded to 192
#define ZM_OFF   3328      // 32 rods x 5  -> padded to 192
#define BUF_DW   3520      // dwords per buffer; 2 buffers = 28160 B LDS

#define N_MS_I  37         // staging instructions per region per chunk
#define N_VIN_I 7
#define N_SC_I  5
#define N_NZ_I  3
#define N_STAGE (N_MS_I + N_VIN_I + N_SC_I + 2*N_NZ_I)   // = 55 (vmcnt-counted)
static_assert(N_STAGE == 55, "vmcnt literal must match");

// last valid flat dword index of each tensor (address-validity clamp; the
// overhang data lands in LDS pad slots that compute never reads)
#define MS_LAST  (2*BATCH*NE*9 - 1)
#define VIN_LAST (BATCH*(NE+1)*3 - 1)
#define SC_LAST  (2*BATCH*NE - 1)
#define NZ_LAST  (BATCH*NE - 1)

typedef const __attribute__((address_space(1))) void* gp_t;
typedef __attribute__((address_space(3))) void* lp_t;

__device__ __forceinline__ int imin(int a, int b) { return a < b ? a : b; }

__global__ __launch_bounds__(64, 1) void rod_kernel(
    const float* __restrict__ vin_g,
    const float* __restrict__ nl_g,
    const float* __restrict__ sc_g,
    const float* __restrict__ ms_g,
    const float* __restrict__ zm_g,
    float* __restrict__ vout_g) {
  __shared__ float smem[2 * BUF_DW];
  const int l = threadIdx.x;
  const int rodbase = blockIdx.x * RODS;
  const int msrow0 = 2 * rodbase * (NE * 9);

  // ---- loop-invariant per-lane staging indices (static-indexed arrays) ----
  int pre_ms[N_MS_I], pre_vin[N_VIN_I], pre_sc[N_SC_I], pre_nz[N_NZ_I];
#pragma unroll
  for (int i = 0; i < N_MS_I; ++i) {          // d -> (row<64, off<37)
    int d = i * 64 + l, row = d / 37, off = d - row * 37;
    pre_ms[i] = msrow0 + row * (NE * 9) + off;            // + 36c at stage time
  }
#pragma unroll
  for (int i = 0; i < N_VIN_I; ++i) {         // d -> (rod, off<13)
    int d = i * 64 + l, r = d / 13, off = d - r * 13;
    pre_vin[i] = (rodbase + r) * 384 + off;               // + 12c+3
  }
#pragma unroll
  for (int i = 0; i < N_SC_I; ++i) {          // d -> (row<64, off<5)
    int d = i * 64 + l, row = d / 5, off = d - row * 5;
    pre_sc[i] = (2 * rodbase + row) * NE + off;           // + 4c
  }
#pragma unroll
  for (int i = 0; i < N_NZ_I; ++i) {          // d -> (rod, off<5)
    int d = i * 64 + l, r = d / 5, off = d - r * 5;
    pre_nz[i] = (rodbase + r) * NE + off;                 // + 4c
  }

  auto STAGE = [&](int cs, int bufdw) {
    const int a36 = 36 * cs, a12 = 12 * cs + 3, a4 = 4 * cs;
#pragma unroll
    for (int i = 0; i < N_MS_I; ++i) {
      int gi = imin(pre_ms[i] + a36, MS_LAST);
      __builtin_amdgcn_global_load_lds((gp_t)(ms_g + gi),
          (lp_t)(smem + bufdw + MS_OFF + i * 64), 4, 0, 0);
    }
#pragma unroll
    for (int i = 0; i < N_VIN_I; ++i) {
      int gi = imin(pre_vin[i] + a12, VIN_LAST);
      __builtin_amdgcn_global_load_lds((gp_t)(vin_g + gi),
          (lp_t)(smem + bufdw + VIN_OFF + i * 64), 4, 0, 0);
    }
#pragma unroll
    for (int i = 0; i < N_SC_I; ++i) {
      int gi = imin(pre_sc[i] + a4, SC_LAST);
      __builtin_amdgcn_global_load_lds((gp_t)(sc_g + gi),
          (lp_t)(smem + bufdw + SC_OFF + i * 64), 4, 0, 0);
    }
#pragma unroll
    for (int i = 0; i < N_NZ_I; ++i) {
      int gi = imin(pre_nz[i] + a4, NZ_LAST);
      __builtin_amdgcn_global_load_lds((gp_t)(nl_g + gi),
          (lp_t)(smem + bufdw + NL_OFF + i * 64), 4, 0, 0);
    }
#pragma unroll
    for (int i = 0; i < N_NZ_I; ++i) {
      int gi = imin(pre_nz[i] + a4, NZ_LAST);
      __builtin_amdgcn_global_load_lds((gp_t)(zm_g + gi),
          (lp_t)(smem + bufdw + ZM_OFF + i * 64), 4, 0, 0);
    }
  };

  // carry vertex (lanes >=32 compute a harmless duplicate of rod 31)
  float px, py, pz;
  {
    const float* v0 = vin_g + (size_t)(rodbase + imin(l, RODS - 1)) * 384;
    px = v0[0]; py = v0[1]; pz = v0[2];
  }

  STAGE(0, 0);
  STAGE(1, BUF_DW);

  for (int c = 0; c < 31; ++c) {
    // wait for chunk c's staging (issued 1 period ago); allow the newest 55
    // (chunk c+1's staging) to stay in flight — never drain to 0 mid-loop.
    asm volatile("s_waitcnt vmcnt(55)" ::: "memory");
    __builtin_amdgcn_sched_barrier(0);
    const int bufdw = (c & 1) ? BUF_DW : 0;
    if (l < RODS) {
      const float* m0p = smem + bufdw + MS_OFF + 74 * l;   // row 2l
      const float* m1p = m0p + 37;                         // row 2l+1
      const float* vp  = smem + bufdw + VIN_OFF + 13 * l;
      const float* s0p = smem + bufdw + SC_OFF + 10 * l;
      const float* s1p = s0p + 5;
      const float* nlp = smem + bufdw + NL_OFF + 5 * l;
      const float* zmp = smem + bufdw + ZM_OFF + 5 * l;
      float out[12];
#pragma unroll
      for (int k = 0; k < 4; ++k) {
        float qx = vp[3*k+0], qy = vp[3*k+1], qz = vp[3*k+2];
        float zmv = zmp[k], nlv = nlp[k];
        float ex = (qx - px) * zmv, ey = (qy - py) * zmv, ez = (qz - pz) * zmv;
        float nlsq = nlv * nlv;
        float denom = nlsq + ex*ex + ey*ey + ez*ez;
        float lam = 1.0f - 2.0f * nlsq * __builtin_amdgcn_rcpf(denom);
        float f0 = lam * __builtin_amdgcn_rcpf(s0p[k]);
        float f1 = lam * __builtin_amdgcn_rcpf(s1p[k]);
        const float* m0 = m0p + 9*k;
        const float* m1 = m1p + 9*k;
        float u0x = (m0[0]*ex + m0[1]*ey + m0[2]*ez) * f0;
        float u0y = (m0[3]*ex + m0[4]*ey + m0[5]*ez) * f0;
        float u0z = (m0[6]*ex + m0[7]*ey + m0[8]*ez) * f0;
        float u1x = (m1[0]*ex + m1[1]*ey + m1[2]*ez) * f1;
        float u1y = (m1[3]*ex + m1[4]*ey + m1[5]*ez) * f1;
        float u1z = (m1[6]*ex + m1[7]*ey + m1[8]*ez) * f1;
        out[3*k+0] = px + u0x;
        out[3*k+1] = py + u0y;
        out[3*k+2] = pz + u0z;
        px = qx + u1x; py = qy + u1y; pz = qz + u1z;
      }
      float4* po = (float4*)(vout_g + (size_t)(rodbase + l) * 384 + 12 * c);
      po[0] = make_float4(out[0], out[1], out[2],  out[3]);
      po[1] = make_float4(out[4], out[5], out[6],  out[7]);
      po[2] = make_float4(out[8], out[9], out[10], out[11]);
    }
    __builtin_amdgcn_sched_barrier(0);
    asm volatile("s_waitcnt lgkmcnt(0)" ::: "memory");     // buffer fully read
    if (c + 2 < NCH) STAGE(c + 2, bufdw);                  // refill freed buffer
  }

  // ---- tail chunk c=31: edges 124..126 (3 edges) + final vertex ----
  asm volatile("s_waitcnt vmcnt(0)" ::: "memory");
  __builtin_amdgcn_sched_barrier(0);
  if (l < RODS) {
    const int bufdw = BUF_DW;   // 31 & 1
    const float* m0p = smem + bufdw + MS_OFF + 74 * l;
    const float* m1p = m0p + 37;
    const float* vp  = smem + bufdw + VIN_OFF + 13 * l;
    const float* s0p = smem + bufdw + SC_OFF + 10 * l;
    const float* s1p = s0p + 5;
    const float* nlp = smem + bufdw + NL_OFF + 5 * l;
    const float* zmp = smem + bufdw + ZM_OFF + 5 * l;
    float out[9];
#pragma unroll
    for (int k = 0; k < 3; ++k) {
      float qx = vp[3*k+0], qy = vp[3*k+1], qz = vp[3*k+2];
      float zmv = zmp[k], nlv = nlp[k];
      float ex = (qx - px) * zmv, ey = (qy - py) * zmv, ez = (qz - pz) * zmv;
      float nlsq = nlv * nlv;
      float denom = nlsq + ex*ex + ey*ey + ez*ez;
      float lam = 1.0f - 2.0f * nlsq * __builtin_amdgcn_rcpf(denom);
      float f0 = lam * __builtin_amdgcn_rcpf(s0p[k]);
      float f1 = lam * __builtin_amdgcn_rcpf(s1p[k]);
      const float* m0 = m0p + 9*k;
      const float* m1 = m1p + 9*k;
      float u0x = (m0[0]*ex + m0[1]*ey + m0[2]*ez) * f0;
      float u0y = (m0[3]*ex + m0[4]*ey + m0[5]*ez) * f0;
      float u0z = (m0[6]*ex + m0[7]*ey + m0[8]*ez) * f0;
      float u1x = (m1[0]*ex + m1[1]*ey + m1[2]*ez) * f1;
      float u1y = (m1[3]*ex + m1[4]*ey + m1[5]*ez) * f1;
      float u1z = (m1[6]*ex + m1[7]*ey + m1[8]*ez) * f1;
      out[3*k+0] = px + u0x;
      out[3*k+1] = py + u0y;
      out[3*k+2] = pz + u0z;
      px = qx + u1x; py = qy + u1y; pz = qz + u1z;
    }
    float4* po = (float4*)(vout_g + (size_t)(rodbase + l) * 384 + 372);
    po[0] = make_float4(out[0], out[1], out[2], out[3]);
    po[1] = make_float4(out[4], out[5], out[6], out[7]);
    po[2] = make_float4(out[8], px, py, pz);   // v126.z + final vertex 127
  }
}

extern "C" void kernel_launch(void* const* d_in, const int* in_sizes, int n_in,
                              void* d_out, int out_size, void* d_ws, size_t ws_size,
                              hipStream_t stream) {
  const float* vin = (const float*)d_in[0];   // current_vertices (B,N,3)
  const float* nl  = (const float*)d_in[1];   // nominal_length   (B,N-1)
  const float* sc  = (const float*)d_in[2];   // scale            (2B,N-1)
  const float* ms  = (const float*)d_in[3];   // mass_scale       (2B,N-1,3,3)
  const float* zm  = (const float*)d_in[4];   // zero_mask_num    (B,N-1)
  float* vout = (float*)d_out;                // (B,N,3)

  // 256 blocks x 64 threads: one wave per CU; all 64 lanes stage coalesced
  // via global_load_lds, 32 lanes run 32 independent rod chains from LDS.
  dim3 grid(BATCH / RODS);
  dim3 block(64);
  hipLaunchKernelGGL(rod_kernel, grid, block, 0, stream, vin, nl, sc, ms, zm, vout);
}